// Round 9
// baseline (239.237 us; speedup 1.0000x reference)
//
#include <hip/hip_runtime.h>
#include <math.h>

#define N_NODES 10000
#define N_EDGES 320000
#define CAP 128        // max in-degree bucket capacity (mean 32, +17 sigma)
#define TN 8192        // gate table samples over [0, 8]; step = 1/1024
#define TSCALE 1024.0f // TN / 8
#define BK_BLOCKS 1250 // 1250*256 = 320000 edges
#define AI_BLOCKS 40   // 40*256 >= 10000 nodes
#define TB_BLOCKS 33   // 33*256 >= TN+1 table entries

__device__ __forceinline__ float silu_f(float x) {
    return x / (1.0f + __expf(-x));
}

// ---------------- kernel 1 (fused): bucket insert + node Ai MLP + gates table --
// All three paths keep live state <= ~40 VGPRs, so the occupancy-targeting
// allocator (caps at 48-64 VGPR: r2/r4/r8 evidence) cannot spill, and there is
// no large per-thread array for promote-alloca to dump into LDS (r7 lesson).
//   blocks [0,1250)     : bucket insert (e,src) by dst  -- latency-bound
//   blocks [1250,1290)  : node Ai MLP
//   blocks [1290,1323)  : gates(r) table, i-outer / j-quarter restructure
__global__ __launch_bounds__(256) void bucket_prep_kernel(
    const int* __restrict__ edge_src, const int* __restrict__ edge_dst,
    const float* __restrict__ atom_emb, const int* __restrict__ A,
    const float* __restrict__ w1, const float* __restrict__ b1,
    const float* __restrict__ w2, const float* __restrict__ b2,
    const float* __restrict__ fw1, const float* __restrict__ fb1,
    const float* __restrict__ fw2, const float* __restrict__ fb2,
    const float* __restrict__ fw3, const float* __restrict__ fb3,
    float* __restrict__ Ai, float4* __restrict__ tab,
    int* __restrict__ deg, int2* __restrict__ elist)
{
    int bid = blockIdx.x;
    if (bid < BK_BLOCKS) {
        // ---- bucket insert: the only per-edge scatter work ----
        int e = bid * 256 + threadIdx.x;
        int dst = edge_dst[e];
        int src = edge_src[e];       // coalesced here; scattered in gather otherwise
        int p = atomicAdd(&deg[dst], 1);
        if (p < CAP) elist[dst * CAP + p] = make_int2(e, src);
        return;
    }
    if (bid < BK_BLOCKS + AI_BLOCKS) {
        // ---- node Ai = mlp(atom_emb[A]) ----
        int n = (bid - BK_BLOCKS) * 256 + threadIdx.x;
        if (n >= N_NODES) return;
        int a = A[n];
        float emb[16];
        #pragma unroll
        for (int i = 0; i < 16; ++i) emb[i] = atom_emb[a * 16 + i];
        float acc[8];
        #pragma unroll
        for (int o = 0; o < 8; ++o) acc[o] = b2[o];
        #pragma unroll 4
        for (int j = 0; j < 64; ++j) {
            float s0 = b1[j], s1 = 0.f;
            #pragma unroll
            for (int i = 0; i < 16; i += 2) {
                s0 += emb[i]     * w1[i * 64 + j];
                s1 += emb[i + 1] * w1[(i + 1) * 64 + j];
            }
            float h = silu_f(s0 + s1);
            #pragma unroll
            for (int o = 0; o < 8; ++o) acc[o] += h * w2[j * 8 + o];
        }
        #pragma unroll
        for (int o = 0; o < 8; ++o) Ai[n * 8 + o] = acc[o];
        return;
    }

    // ---- gates(r) table: t in [0, TN] inclusive ----
    // i-outer / j-quarter: never materialize g1[64]; recompute g1[i] per pass
    // (10 FMA + silu) and hold only acc[16]. Peak live ~40 regs -> no spill.
    int t = (bid - BK_BLOCKS - AI_BLOCKS) * 256 + threadIdx.x;
    if (t > TN) return;
    float r = (float)t * (1.0f / TSCALE);

    float rb[10];
    {
        float x = r * 2.2f;
        #pragma unroll
        for (int i = 0; i < 10; ++i) {
            float d = x - (float)(i + 1);
            rb[i] = __expf(-d * d) * 2.8234622f;
        }
    }

    float gate0 = fb3[0], gate3 = fb3[3], gate9 = fb3[9];
    #pragma unroll 1
    for (int q = 0; q < 4; ++q) {
        float acc[16];
        #pragma unroll
        for (int j = 0; j < 16; ++j) acc[j] = fb2[q * 16 + j];
        #pragma unroll 1
        for (int i = 0; i < 64; ++i) {
            float s = fb1[i];
            #pragma unroll
            for (int k = 0; k < 10; ++k) s += rb[k] * fw1[k * 64 + i];
            float g1i = silu_f(s);
            const float* w2row = fw2 + i * 64 + q * 16;
            #pragma unroll
            for (int j = 0; j < 16; ++j) acc[j] += g1i * w2row[j];
        }
        #pragma unroll
        for (int j = 0; j < 16; ++j) {
            float h = silu_f(acc[j]);
            int jj = q * 16 + j;
            gate0 += h * fw3[jj * 15 + 0];
            gate3 += h * fw3[jj * 15 + 3];
            gate9 += h * fw3[jj * 15 + 9];
        }
    }
    tab[t] = make_float4(gate0, gate3, gate9, 0.f);
}

// ---------------- kernel 2: fused gather (inline geometry) + contraction --------
// Block = 256 threads = 4 waves = 4 nodes; lane = slot*8 + u.
// Phase 1: each slot-group of 8 lanes processes one edge: recompute edge vector,
//          table-lerp gates, Y harmonics (redundant across the 8 u-lanes but the
//          VALU is otherwise idle: r6 showed VALUBusy=1%), accumulate
//          acc[k] += q[k]*Ai[src][u]; shfl-reduce over slots -> M[u][9] in LDS.
// Phase 2: 128 threads contract with tp_w and write out[n][288].
__global__ __launch_bounds__(256) void gather_out_kernel(
    const int* __restrict__ deg, const int2* __restrict__ elist,
    const float* __restrict__ pos, const float* __restrict__ edge_shifts,
    const float* __restrict__ cell, const int* __restrict__ batch,
    const float4* __restrict__ tab, const float* __restrict__ Ai,
    const float* __restrict__ tp_w, float* __restrict__ out)
{
    __shared__ float sM[4][72];
    __shared__ float sA[4][8];
    int tid = threadIdx.x;
    int lane = tid & 63;
    int wv = tid >> 6;
    int nodeBase = blockIdx.x * 4;
    int n1 = nodeBase + wv;
    int u1 = lane & 7;
    int slot = lane >> 3;

    int d = deg[n1];
    int dc = d > CAP ? CAP : d;

    // dst position is loop-invariant (dst == n1)
    float px = pos[n1 * 3 + 0], py = pos[n1 * 3 + 1], pz = pos[n1 * 3 + 2];

    const float SQ3 = 1.7320508075688772f;
    const float SQ15 = 3.872983346207417f;
    const float SQ5H = 1.1180339887498949f;   // sqrt(5)/2

    float acc[9];
    #pragma unroll
    for (int k = 0; k < 9; ++k) acc[k] = 0.f;

    const int2* el = elist + n1 * CAP;
    for (int i = slot; i < dc; i += 8) {
        int2 es = el[i];
        int e = es.x, src = es.y;

        float s0 = edge_shifts[e * 3 + 0];
        float s1 = edge_shifts[e * 3 + 1];
        float s2 = edge_shifts[e * 3 + 2];
        int b = batch[src];
        const float* Cb = cell + b * 9;
        float vx = px - pos[src * 3 + 0] + s0 * Cb[0] + s1 * Cb[3] + s2 * Cb[6];
        float vy = py - pos[src * 3 + 1] + s0 * Cb[1] + s1 * Cb[4] + s2 * Cb[7];
        float vz = pz - pos[src * 3 + 2] + s0 * Cb[2] + s1 * Cb[5] + s2 * Cb[8];

        float r = sqrtf(vx * vx + vy * vy + vz * vz);
        float rinv = 1.0f / fmaxf(r, 1e-8f);
        float nx = vx * rinv, ny = vy * rinv, nz = vz * rinv;

        float tf = fminf(r * TSCALE, (float)(TN - 1));
        int   i0 = (int)tf;
        float fr = tf - (float)i0;
        float4 ga = tab[i0];
        float4 gb = tab[i0 + 1];
        float gate0 = ga.x + fr * (gb.x - ga.x);
        float gate3 = ga.y + fr * (gb.y - ga.y);
        float gate9 = ga.z + fr * (gb.z - ga.z);

        float au = Ai[src * 8 + u1];

        acc[0] += gate0 * au;
        float g3a = gate3 * au;
        acc[1] += g3a * (SQ3 * nx);
        acc[2] += g3a * (SQ3 * ny);
        acc[3] += g3a * (SQ3 * nz);
        float g9a = gate9 * au;
        acc[4] += g9a * (SQ15 * nx * ny);
        acc[5] += g9a * (SQ15 * ny * nz);
        acc[6] += g9a * (SQ5H * (3.0f * nz * nz - 1.0f));
        acc[7] += g9a * (SQ15 * nx * nz);
        acc[8] += g9a * (0.5f * SQ15 * (nx * nx - ny * ny));
    }

    #pragma unroll
    for (int m = 8; m < 64; m <<= 1) {
        #pragma unroll
        for (int k = 0; k < 9; ++k) acc[k] += __shfl_xor(acc[k], m, 64);
    }

    if (slot == 0) {
        #pragma unroll
        for (int k = 0; k < 9; ++k) sM[wv][u1 * 9 + k] = acc[k];
    }
    if (tid < 32) sA[tid >> 3][tid & 7] = Ai[nodeBase * 8 + tid];
    __syncthreads();

    if (tid >= 128) return;
    int ln = tid >> 5, w = tid & 31;
    int n = nodeBase + ln;

    float a[8];
    #pragma unroll
    for (int v = 0; v < 8; ++v) a[v] = sA[ln][v];
    float inv = 1.0f / fmaxf((float)deg[n], 1.0f);

    const float* W0 = tp_w + 0 * 2048;   // path (0,0,0)
    const float* W3 = tp_w + 3 * 2048;   // path (1,0,1)
    const float* W9 = tp_w + 9 * 2048;   // path (2,0,2)

    // l=0 block (32 floats at offset 0)
    {
        float o0 = 0.f;
        #pragma unroll
        for (int u = 0; u < 8; ++u) {
            float c = 0.f;
            #pragma unroll
            for (int v = 0; v < 8; ++v) c += a[v] * W0[(u * 8 + v) * 32 + w];
            o0 += sM[ln][u * 9] * c;
        }
        out[n * 288 + w] = o0 * inv;
    }
    // l=1 block (96 floats at offset 32), layout [w][k], k<3
    {
        float o1[3] = {0.f, 0.f, 0.f};
        #pragma unroll
        for (int u = 0; u < 8; ++u) {
            float c = 0.f;
            #pragma unroll
            for (int v = 0; v < 8; ++v) c += a[v] * W3[(u * 8 + v) * 32 + w];
            #pragma unroll
            for (int k = 0; k < 3; ++k) o1[k] += sM[ln][u * 9 + 1 + k] * c;
        }
        #pragma unroll
        for (int k = 0; k < 3; ++k) out[n * 288 + 32 + w * 3 + k] = o1[k] * inv;
    }
    // l=2 block (160 floats at offset 128), layout [w][k], k<5
    {
        float o2[5] = {0.f, 0.f, 0.f, 0.f, 0.f};
        #pragma unroll
        for (int u = 0; u < 8; ++u) {
            float c = 0.f;
            #pragma unroll
            for (int v = 0; v < 8; ++v) c += a[v] * W9[(u * 8 + v) * 32 + w];
            #pragma unroll
            for (int k = 0; k < 5; ++k) o2[k] += sM[ln][u * 9 + 4 + k] * c;
        }
        #pragma unroll
        for (int k = 0; k < 5; ++k) out[n * 288 + 128 + w * 5 + k] = o2[k] * inv;
    }
}

// ---------------- launch ---------------------------------------------------------
extern "C" void kernel_launch(void* const* d_in, const int* in_sizes, int n_in,
                              void* d_out, int out_size, void* d_ws, size_t ws_size,
                              hipStream_t stream) {
    const float* pos         = (const float*)d_in[0];
    const float* edge_shifts = (const float*)d_in[1];
    const float* cell        = (const float*)d_in[2];
    const float* atom_emb    = (const float*)d_in[3];
    const float* mlp_w1      = (const float*)d_in[4];
    const float* mlp_b1      = (const float*)d_in[5];
    const float* mlp_w2      = (const float*)d_in[6];
    const float* mlp_b2      = (const float*)d_in[7];
    const float* fc_w1       = (const float*)d_in[8];
    const float* fc_b1       = (const float*)d_in[9];
    const float* fc_w2       = (const float*)d_in[10];
    const float* fc_b2       = (const float*)d_in[11];
    const float* fc_w3       = (const float*)d_in[12];
    const float* fc_b3       = (const float*)d_in[13];
    const float* tp_w        = (const float*)d_in[14];
    const int*   A           = (const int*)d_in[15];
    const int*   batch       = (const int*)d_in[16];
    const int*   edge_src    = (const int*)d_in[17];
    const int*   edge_dst    = (const int*)d_in[18];
    float* out = (float*)d_out;

    // workspace layout (16B aligned):
    // floats: Ai[80000] | tab[(TN+1)*4] ; ints: deg[10000] | elist int2[10000*128]
    float*  Ai  = (float*)d_ws;
    float4* tab = (float4*)(Ai + N_NODES * 8);
    int*    deg   = (int*)(tab + (TN + 1));
    int2*   elist = (int2*)(deg + N_NODES);
    // total: ~10.8 MB

    hipMemsetAsync(deg, 0, N_NODES * sizeof(int), stream);

    bucket_prep_kernel<<<BK_BLOCKS + AI_BLOCKS + TB_BLOCKS, 256, 0, stream>>>(
        edge_src, edge_dst, atom_emb, A, mlp_w1, mlp_b1, mlp_w2, mlp_b2,
        fc_w1, fc_b1, fc_w2, fc_b2, fc_w3, fc_b3, Ai, tab, deg, elist);

    gather_out_kernel<<<N_NODES / 4, 256, 0, stream>>>(
        deg, elist, pos, edge_shifts, cell, batch, tab, Ai, tp_w, out);
}